// Round 14
// baseline (108.831 us; speedup 1.0000x reference)
//
#include <hip/hip_runtime.h>
#include <cmath>

#define BB  256
#define FPN 80
#define SPN 160
#define NPGc 242                 // FPN+SPN+2
#define NNc (BB*NPGc)            // 61952 = 242 * 256
#define NBKT 242                 // dst >> 8 buckets
#define CAPSH 13                 // 8192 dense capacity per bucket (avg 4132)
#define BCAP (1<<CAPSH)
#define NSLOT 768                // partition blocks
#define SLOTCAP 32               // per (block,bucket) slot: 128B = 2 exclusive cache lines
#define SLABSTRIDE (NSLOT*SLOTCAP)
#define NEMB 1936
#define NQUAD (BB*240/4)         // 15360
#define AGGB 2048                // agg grid (grid-stride over quads)

// XOR-swizzle for [N][128] bf16 LDS tiles (256B rows): kills 16-way ds conflicts (G4/T2).
#define SWZB(b) ((b) ^ ((((b) >> 8) & 7) << 4))

typedef __attribute__((ext_vector_type(8))) short bf16x8;
typedef __attribute__((ext_vector_type(4))) float f32x4;

static __device__ __forceinline__ unsigned short f2bf(float f) {
    unsigned u = __float_as_uint(f);
    unsigned r = (u + 0x7fffu + ((u >> 16) & 1u)) >> 16;
    return (unsigned short)r;
}
static __device__ __forceinline__ float bflo(unsigned u) { return __uint_as_float(u << 16); }
static __device__ __forceinline__ float bfhi(unsigned u) { return __uint_as_float(u & 0xffff0000u); }
static __device__ __forceinline__ unsigned pk2(float a, float b) {
    return (unsigned)f2bf(a) | ((unsigned)f2bf(b) << 16);
}

struct P {
    const int *fid, *sid, *uid, *iid, *esrc, *edst;
    const float *user_tab, *item_tab, *feat_tab, *sent_tab;
    const float *Wf, *Ws, *Wu, *Wi, *Wg, *attn_l, *attn_r;
    const float *w_sent, *b_sent, *w_feat, *b_feat;
    int E;
    unsigned short *WcT, *zb;
    float *el, *er;
    int *cnt, *off, *cntM;
    unsigned *bktd;
    unsigned short *srcs16;
    float *out;
};

// LDS shapes
struct SortSh {                      // ~49 KB: single-pass raw staging
    int h[256]; int top;
    unsigned raw[BCAP];              // 32 KB
    unsigned short s16[BCAP];        // 16 KB
};
struct EmbSh  { unsigned short sWt[128 * 128], sE[32 * 128], sZ[32 * 128]; };    // 48 KB
union  ShFb   { SortSh sort; EmbSh emb; };
struct AggSh  { int ssrc[4][64]; float sex[4][64][4]; };                         // 5 KB

// ---------------- partition: private slots, no global atomics, no shared cache lines ----------------
static __device__ __forceinline__ void part_body(const P& p, int b, int t, int* h)
{
    for (int j = t; j < NBKT; j += 256) h[j] = 0;
    __syncthreads();
    int CH = (p.E + NSLOT - 1) / NSLOT;
    int start = b * CH, lim = min(start + CH, p.E);
    for (int i = start + t; i < lim; i += 256) {
        int d = p.edst[i];
        int bk = d >> 8;
        int idx = atomicAdd(&h[bk], 1);
        if (idx < SLOTCAP)
            p.bktd[bk * SLABSTRIDE + b * SLOTCAP + idx] =
                ((unsigned)(d & 255) << 16) | (unsigned)p.esrc[i];
    }
    __syncthreads();
    for (int j = t; j < NBKT; j += 256) p.cntM[b * NBKT + j] = min(h[j], SLOTCAP);
}

static __device__ __forceinline__ void wct_body(const P& p, int wb, int t)
{
    int type = wb >> 4;
    int rowbase = (wb & 15) * 8;
    const float* Wt = type == 0 ? p.Wf : type == 1 ? p.Ws : type == 2 ? p.Wu : p.Wi;
    int j = t & 127, half = t >> 7;
    for (int i = rowbase + half; i < rowbase + 8; i += 2) {
        float acc = 0.f;
        for (int k = 0; k < 128; ++k)
            acc = fmaf(Wt[i * 128 + k], p.Wg[k * 128 + j], acc);
        p.WcT[type * 16384 + j * 128 + i] = f2bf(acc);
    }
}

// single-pass: slab -> LDS raw (one global read), then count/scan/scatter from LDS
static __device__ __forceinline__ void bsort_body(const P& p, int bk, int t, SortSh* sort)
{
    int* h = sort->h;
    if (t == 0) sort->top = 0;
    h[t] = 0;
    __syncthreads();
    for (int sl = t; sl < NSLOT; sl += 256) {
        int c = p.cntM[sl * NBKT + bk];
        if (c > 0) {
            int pos = atomicAdd(&sort->top, c);
            const unsigned* slot = p.bktd + bk * SLABSTRIDE + sl * SLOTCAP;
            for (int i = 0; i < c; ++i) sort->raw[pos + i] = slot[i];
        }
    }
    __syncthreads();
    int m = sort->top;
    for (int i = t; i < m; i += 256)
        atomicAdd(&h[(sort->raw[i] >> 16) & 255], 1);
    __syncthreads();
    int myc = h[t];
    for (int d = 1; d < 256; d <<= 1) {
        int add = (t >= d) ? h[t - d] : 0;
        __syncthreads();
        h[t] += add;
        __syncthreads();
    }
    int node = (bk << 8) + t;
    p.off[node] = (bk << CAPSH) + h[t] - myc;
    p.cnt[node] = myc;
    __syncthreads();
    for (int i = t; i < m; i += 256) {
        unsigned u = sort->raw[i];
        int pos = atomicSub(&h[(u >> 16) & 255], 1) - 1;
        sort->s16[pos] = (unsigned short)(u & 0xFFFFu);
    }
    __syncthreads();
    for (int i = t; i < m; i += 256) p.srcs16[(bk << CAPSH) + i] = sort->s16[i];
}

// ---------------- aggregate one quad (4 nodes, 1 per wave) ----------------
static __device__ __forceinline__ void agg_quad(const P& p, int qd, int t, AggSh* ag)
{
    int w = t >> 6, lane = t & 63;
    int grp = lane >> 4, li = lane & 15;
    int hm = li >> 2;
    int oid = qd * 4 + w;
    int g = oid / 240, local = oid % 240;
    int n = g * NPGc + local;
    int beg = p.off[n], deg = p.cnt[n];
    const float4 er4 = *(const float4*)(p.er + n * 4);

    float4 den = {0, 0, 0, 0};
    float acc[8] = {0, 0, 0, 0, 0, 0, 0, 0};

    for (int chunk = 0; chunk < deg; chunk += 64) {
        int m = min(64, deg - chunk);
        if (lane < m) {
            int s = (int)p.srcs16[beg + chunk + lane];
            float4 l4v = *(const float4*)(p.el + s * 4);
            float4 e;
            e.x = l4v.x + er4.x; e.y = l4v.y + er4.y;
            e.z = l4v.z + er4.z; e.w = l4v.w + er4.w;
            e.x = e.x > 0.f ? e.x : 0.2f * e.x;
            e.y = e.y > 0.f ? e.y : 0.2f * e.y;
            e.z = e.z > 0.f ? e.z : 0.2f * e.z;
            e.w = e.w > 0.f ? e.w : 0.2f * e.w;
            float4 ex;
            ex.x = expf(e.x); ex.y = expf(e.y); ex.z = expf(e.z); ex.w = expf(e.w);
            den.x += ex.x; den.y += ex.y; den.z += ex.z; den.w += ex.w;
            ag->ssrc[w][lane] = s;
            *(float4*)&ag->sex[w][lane][0] = ex;
        }
        for (int c0 = 0; c0 < m; c0 += 8) {
            int j0 = c0 + grp, j1 = c0 + 4 + grp;
            float ew0 = 0.f, ew1 = 0.f; int s0 = 0, s1 = 0;
            if (j0 < m) { s0 = ag->ssrc[w][j0]; ew0 = ag->sex[w][j0][hm]; }
            if (j1 < m) { s1 = ag->ssrc[w][j1]; ew1 = ag->sex[w][j1][hm]; }
            uint4 u0 = *(const uint4*)(p.zb + (size_t)s0 * 128 + li * 8);
            uint4 u1 = *(const uint4*)(p.zb + (size_t)s1 * 128 + li * 8);
            acc[0] = fmaf(ew0, bflo(u0.x), acc[0]);
            acc[1] = fmaf(ew0, bfhi(u0.x), acc[1]);
            acc[2] = fmaf(ew0, bflo(u0.y), acc[2]);
            acc[3] = fmaf(ew0, bfhi(u0.y), acc[3]);
            acc[4] = fmaf(ew0, bflo(u0.z), acc[4]);
            acc[5] = fmaf(ew0, bfhi(u0.z), acc[5]);
            acc[6] = fmaf(ew0, bflo(u0.w), acc[6]);
            acc[7] = fmaf(ew0, bfhi(u0.w), acc[7]);
            acc[0] = fmaf(ew1, bflo(u1.x), acc[0]);
            acc[1] = fmaf(ew1, bfhi(u1.x), acc[1]);
            acc[2] = fmaf(ew1, bflo(u1.y), acc[2]);
            acc[3] = fmaf(ew1, bfhi(u1.y), acc[3]);
            acc[4] = fmaf(ew1, bflo(u1.z), acc[4]);
            acc[5] = fmaf(ew1, bfhi(u1.z), acc[5]);
            acc[6] = fmaf(ew1, bflo(u1.w), acc[6]);
            acc[7] = fmaf(ew1, bfhi(u1.w), acc[7]);
        }
    }

#pragma unroll
    for (int k = 0; k < 8; ++k) {
        acc[k] += __shfl_xor(acc[k], 16);
        acc[k] += __shfl_xor(acc[k], 32);
    }
#pragma unroll
    for (int d = 1; d < 64; d <<= 1) {
        den.x += __shfl_xor(den.x, d); den.y += __shfl_xor(den.y, d);
        den.z += __shfl_xor(den.z, d); den.w += __shfl_xor(den.w, d);
    }

    float dh = (hm == 0 ? den.x : hm == 1 ? den.y : hm == 2 ? den.z : den.w) + 1e-9f;
    float hv[8];
#pragma unroll
    for (int k = 0; k < 8; ++k) {
        float v = acc[k] / dh;
        hv[k] = v > 0.f ? v : expm1f(v);
    }

    const float* wv; float bias; int oidx;
    if (local < FPN) { wv = p.w_feat; bias = p.b_feat[0]; oidx = BB * SPN + g * FPN + local; }
    else             { wv = p.w_sent; bias = p.b_sent[0]; oidx = g * SPN + (local - FPN); }

    float4 wa = *(const float4*)(wv + li * 8);
    float4 wb = *(const float4*)(wv + li * 8 + 4);
    float pr = hv[0] * wa.x + hv[1] * wa.y + hv[2] * wa.z + hv[3] * wa.w
             + hv[4] * wb.x + hv[5] * wb.y + hv[6] * wb.z + hv[7] * wb.w;
#pragma unroll
    for (int d = 1; d < 16; d <<= 1) pr += __shfl_xor(pr, d);
    if (lane == 0) p.out[oidx] = pr + bias;
}

// =================== kernels ===================
__global__ __launch_bounds__(256) void fk_part(P p)
{
    __shared__ int h[256];
    int b = blockIdx.x, t = threadIdx.x;
    if (b >= NSLOT) { wct_body(p, b - NSLOT, t); return; }
    part_body(p, b, t, h);
}

__global__ __launch_bounds__(256) void fk_fused(P p)
{
    __shared__ ShFb sh;
    int b = blockIdx.x, t = threadIdx.x;
    if (b < NBKT) { bsort_body(p, b, t, &sh.sort); return; }

    int eb = b - NBKT;
    int type, q0;
    if (eb < 640)       { type = 0; q0 = eb * 32; }
    else if (eb < 1920) { type = 1; q0 = (eb - 640) * 32; }
    else if (eb < 1928) { type = 2; q0 = (eb - 1920) * 32; }
    else                { type = 3; q0 = (eb - 1928) * 32; }

    char* sWb = (char*)sh.emb.sWt;
    char* sEb = (char*)sh.emb.sE;
    char* sZb = (char*)sh.emb.sZ;

    {   // stage WcT slab (32 KB), swizzled writes
        const uint4* src = (const uint4*)(p.WcT + type * 16384);
#pragma unroll
        for (int i = 0; i < 8; ++i) {
            int u = t + i * 256;
            *(uint4*)(sWb + SWZB(u * 16)) = src[u];
        }
    }
    int row = t >> 3, part = t & 7;
    int q = q0 + row;
    int id; const float* tab;
    if (type == 0)      { id = p.fid[q]; tab = p.feat_tab; }
    else if (type == 1) { id = p.sid[q]; tab = p.sent_tab; }
    else if (type == 2) { id = p.uid[q]; tab = p.user_tab; }
    else                { id = p.iid[q]; tab = p.item_tab; }
    {   // stage 32 embedding rows (bf16), swizzled writes
        const float4* gsrc = (const float4*)(tab + (long long)id * 128) + part * 4;
        float4 v0 = gsrc[0], v1 = gsrc[1], v2 = gsrc[2], v3 = gsrc[3];
        uint4 p0 = {pk2(v0.x, v0.y), pk2(v0.z, v0.w), pk2(v1.x, v1.y), pk2(v1.z, v1.w)};
        uint4 p1 = {pk2(v2.x, v2.y), pk2(v2.z, v2.w), pk2(v3.x, v3.y), pk2(v3.z, v3.w)};
        int bo = row * 256 + part * 32;
        *(uint4*)(sEb + SWZB(bo))      = p0;
        *(uint4*)(sEb + SWZB(bo + 16)) = p1;
    }
    __syncthreads();

    auto nodeof = [&](int qq) -> int {
        if (type == 0) return (qq / 80) * NPGc + (qq % 80);
        if (type == 1) return (qq / 160) * NPGc + 80 + (qq % 160);
        if (type == 2) return qq * NPGc + 240;
        return qq * NPGc + 241;
    };

    int lane = t & 63, w2 = t >> 6;
    int l15 = lane & 15, l4 = lane >> 4;
    int cb = w2 * 32;
    f32x4 acc00 = {0, 0, 0, 0}, acc01 = {0, 0, 0, 0};
    f32x4 acc10 = {0, 0, 0, 0}, acc11 = {0, 0, 0, 0};
#pragma unroll
    for (int kb = 0; kb < 4; ++kb) {
        int ko2 = (kb * 32 + l4 * 8) * 2;
        bf16x8 a0 = *(const bf16x8*)(sEb + SWZB(l15 * 256 + ko2));
        bf16x8 a1 = *(const bf16x8*)(sEb + SWZB((l15 + 16) * 256 + ko2));
        bf16x8 b0 = *(const bf16x8*)(sWb + SWZB((cb + l15) * 256 + ko2));
        bf16x8 b1 = *(const bf16x8*)(sWb + SWZB((cb + 16 + l15) * 256 + ko2));
        acc00 = __builtin_amdgcn_mfma_f32_16x16x32_bf16(a0, b0, acc00, 0, 0, 0);
        acc01 = __builtin_amdgcn_mfma_f32_16x16x32_bf16(a0, b1, acc01, 0, 0, 0);
        acc10 = __builtin_amdgcn_mfma_f32_16x16x32_bf16(a1, b0, acc10, 0, 0, 0);
        acc11 = __builtin_amdgcn_mfma_f32_16x16x32_bf16(a1, b1, acc11, 0, 0, 0);
    }

    // el/er directly from accumulators: wave w2 holds exactly head w2's 32 cols.
    {
        const float* alv = p.attn_l + w2 * 32;
        const float* arv = p.attn_r + w2 * 32;
        float a0c = alv[l15], a1c = alv[l15 + 16];
        float r0c = arv[l15], r1c = arv[l15 + 16];
        float pl[8], pr_[8];
#pragma unroll
        for (int reg = 0; reg < 4; ++reg) {
            pl[reg]      = acc00[reg] * a0c + acc01[reg] * a1c;
            pl[4 + reg]  = acc10[reg] * a0c + acc11[reg] * a1c;
            pr_[reg]     = acc00[reg] * r0c + acc01[reg] * r1c;
            pr_[4 + reg] = acc10[reg] * r0c + acc11[reg] * r1c;
        }
#pragma unroll
        for (int d = 1; d < 16; d <<= 1) {
#pragma unroll
            for (int k = 0; k < 8; ++k) {
                pl[k]  += __shfl_xor(pl[k], d);
                pr_[k] += __shfl_xor(pr_[k], d);
            }
        }
        if (l15 == 0) {
#pragma unroll
            for (int k = 0; k < 8; ++k) {
                int rw = l4 * 4 + (k & 3) + ((k >> 2) << 4);
                int nd = nodeof(q0 + rw);
                p.el[nd * 4 + w2] = pl[k];
                p.er[nd * 4 + w2] = pr_[k];
            }
        }
    }

    // z -> LDS (swizzled scalar writes), then coalesced zb copy
#pragma unroll
    for (int reg = 0; reg < 4; ++reg) {
        int r0 = l4 * 4 + reg;
        *(unsigned short*)(sZb + SWZB((r0 * 128 + cb + l15) * 2))              = f2bf(acc00[reg]);
        *(unsigned short*)(sZb + SWZB((r0 * 128 + cb + 16 + l15) * 2))         = f2bf(acc01[reg]);
        *(unsigned short*)(sZb + SWZB(((r0 + 16) * 128 + cb + l15) * 2))       = f2bf(acc10[reg]);
        *(unsigned short*)(sZb + SWZB(((r0 + 16) * 128 + cb + 16 + l15) * 2))  = f2bf(acc11[reg]);
    }
    __syncthreads();
    {
        int nd = nodeof(q0 + row);
        uint4* zdst = (uint4*)(p.zb + (size_t)nd * 128 + part * 16);
        int bo = row * 256 + part * 32;
        zdst[0] = *(const uint4*)(sZb + SWZB(bo));
        zdst[1] = *(const uint4*)(sZb + SWZB(bo + 16));
    }
}

__global__ __launch_bounds__(256) void fk_agg(P p)
{
    __shared__ AggSh ag;
    for (int qd = blockIdx.x; qd < NQUAD; qd += AGGB)
        agg_quad(p, qd, threadIdx.x, &ag);
}

// ---------------- launcher ----------------
extern "C" void kernel_launch(void* const* d_in, const int* in_sizes, int n_in,
                              void* d_out, int out_size, void* d_ws, size_t ws_size,
                              hipStream_t stream)
{
    P p;
    p.fid = (const int*)d_in[0];
    p.sid = (const int*)d_in[1];
    p.uid = (const int*)d_in[2];
    p.iid = (const int*)d_in[3];
    p.esrc = (const int*)d_in[4];
    p.edst = (const int*)d_in[5];
    p.user_tab = (const float*)d_in[6];
    p.item_tab = (const float*)d_in[7];
    p.feat_tab = (const float*)d_in[8];
    p.sent_tab = (const float*)d_in[9];
    p.Wf = (const float*)d_in[10];
    p.Ws = (const float*)d_in[11];
    p.Wu = (const float*)d_in[12];
    p.Wi = (const float*)d_in[13];
    p.Wg = (const float*)d_in[14];
    p.attn_l = (const float*)d_in[15];
    p.attn_r = (const float*)d_in[16];
    p.w_sent = (const float*)d_in[17];
    p.b_sent = (const float*)d_in[18];
    p.w_feat = (const float*)d_in[19];
    p.b_feat = (const float*)d_in[20];
    p.E = in_sizes[4];
    p.out = (float*)d_out;

    char* w = (char*)d_ws;
    auto alloc = [&](size_t bytes) { char* r = w; w += ((bytes + 255) & ~(size_t)255); return r; };
    p.WcT    = (unsigned short*)alloc((size_t)4 * 128 * 128 * sizeof(unsigned short));
    p.zb     = (unsigned short*)alloc((size_t)NNc * 128 * sizeof(unsigned short));
    p.el     = (float*)alloc((size_t)NNc * 4 * sizeof(float));
    p.er     = (float*)alloc((size_t)NNc * 4 * sizeof(float));
    p.cnt    = (int*)alloc((size_t)NNc * sizeof(int));
    p.off    = (int*)alloc((size_t)NNc * sizeof(int));
    p.cntM   = (int*)alloc((size_t)NSLOT * NBKT * sizeof(int));
    p.bktd   = (unsigned*)alloc((size_t)NBKT * SLABSTRIDE * sizeof(unsigned));
    p.srcs16 = (unsigned short*)alloc((size_t)NBKT * BCAP * sizeof(unsigned short));

    hipLaunchKernelGGL(fk_part,  dim3(NSLOT + 64),  dim3(256), 0, stream, p);
    hipLaunchKernelGGL(fk_fused, dim3(NBKT + NEMB), dim3(256), 0, stream, p);
    hipLaunchKernelGGL(fk_agg,   dim3(AGGB),        dim3(256), 0, stream, p);
}

// Round 15
// 104.101 us; speedup vs baseline: 1.0454x; 1.0454x over previous
//
#include <hip/hip_runtime.h>
#include <cmath>

#define BB  256
#define FPN 80
#define SPN 160
#define NPGc 242                 // FPN+SPN+2
#define NNc (BB*NPGc)            // 61952 = 242 * 256
#define NBKT 242                 // dst >> 8 buckets
#define CAPSH 13                 // 8192 dense capacity per bucket (avg 4132)
#define BCAP (1<<CAPSH)
#define NPART 256
#define SLOTCAP 56               // per (block,bucket) slot: lambda=16.1, +10 sigma
#define SLABSTRIDE (NPART*SLOTCAP)   // 14336 entries per bucket slab

typedef __attribute__((ext_vector_type(8))) short bf16x8;
typedef __attribute__((ext_vector_type(4))) float f32x4;

static __device__ __forceinline__ unsigned short f2bf(float f) {
    unsigned u = __float_as_uint(f);
    unsigned r = (u + 0x7fffu + ((u >> 16) & 1u)) >> 16;
    return (unsigned short)r;
}
static __device__ __forceinline__ float bf2f(unsigned short u) {
    return __uint_as_float(((unsigned)u) << 16);
}
static __device__ __forceinline__ float bflo(unsigned u) { return __uint_as_float(u << 16); }
static __device__ __forceinline__ float bfhi(unsigned u) { return __uint_as_float(u & 0xffff0000u); }
static __device__ __forceinline__ unsigned pk2(float a, float b) {
    return (unsigned)f2bf(a) | ((unsigned)f2bf(b) << 16);
}

// ---------------- fused: slot-partition (0..255) + WcT compute (256..319) ----------------
// No global atomics, no pre-init: block b writes its count for every bucket to cntM[bk][b]
// and scatters edges into its private slot bucketed[bk*SLABSTRIDE + b*SLOTCAP + i].
__global__ __launch_bounds__(256) void k_part(
    const int* __restrict__ esrc, const int* __restrict__ edst, int E,
    int* __restrict__ cntM, unsigned* __restrict__ bucketed,
    const float* __restrict__ Wf, const float* __restrict__ Ws,
    const float* __restrict__ Wu, const float* __restrict__ Wi,
    const float* __restrict__ Wg, unsigned short* __restrict__ WcT)
{
    int b = blockIdx.x, t = threadIdx.x;
    if (b >= NPART) {
        // ---- WcT[t][c][k] = bf16((W_t @ W_gat)^T) ----
        int wb = b - NPART;          // 0..63
        int type = wb >> 4;
        int rowbase = (wb & 15) * 8;
        const float* Wt = type == 0 ? Wf : type == 1 ? Ws : type == 2 ? Wu : Wi;
        int j = t & 127;
        int half = t >> 7;
        for (int i = rowbase + half; i < rowbase + 8; i += 2) {
            float acc = 0.f;
            for (int k = 0; k < 128; ++k)
                acc = fmaf(Wt[i * 128 + k], Wg[k * 128 + j], acc);
            WcT[type * 16384 + j * 128 + i] = f2bf(acc);
        }
        return;
    }
    __shared__ int h[NBKT];
    for (int j = t; j < NBKT; j += 256) h[j] = 0;
    __syncthreads();
    int CH = (E + NPART - 1) / NPART;
    int start = b * CH, lim = min(start + CH, E);
    for (int i = start + t; i < lim; i += 256)
        atomicAdd(&h[edst[i] >> 8], 1);
    __syncthreads();
    for (int j = t; j < NBKT; j += 256) {
        cntM[j * NPART + b] = h[j];
        h[j] = 0;
    }
    __syncthreads();
    for (int i = start + t; i < lim; i += 256) {
        int d = edst[i];
        int bk = d >> 8;
        int idx = atomicAdd(&h[bk], 1);
        if (idx < SLOTCAP)
            bucketed[bk * SLABSTRIDE + b * SLOTCAP + idx] =
                ((unsigned)(d & 255) << 16) | (unsigned)esrc[i];
    }
}

// ---------------- fused: bsort blocks (0..241) + MFMA embed blocks (242..2177) ----------------
struct SortSh { int h[256]; int mtot; unsigned short s16[BCAP]; };                // 17 KB
struct EmbSh  { unsigned short sWt[128 * 128], sE[32 * 128], sZ[32 * 128]; };    // 48 KB
union  ShU    { SortSh sort; EmbSh emb; };

__global__ __launch_bounds__(256) void k_fused(
    const int* __restrict__ cntM, const unsigned* __restrict__ bucketed,
    unsigned short* __restrict__ srcs16, int* __restrict__ off, int* __restrict__ cnt,
    const int* __restrict__ fid, const int* __restrict__ sid,
    const int* __restrict__ uid, const int* __restrict__ iid,
    const float* __restrict__ feat_tab, const float* __restrict__ sent_tab,
    const float* __restrict__ user_tab, const float* __restrict__ item_tab,
    const unsigned short* __restrict__ WcT, const float* __restrict__ attn_l,
    const float* __restrict__ attn_r,
    unsigned short* __restrict__ zb, float* __restrict__ el, float* __restrict__ er)
{
    __shared__ ShU sh;
    int b = blockIdx.x, t = threadIdx.x;

    if (b < NBKT) {
        // ---- per-bucket LDS counting sort by dst_low, reading private slots ----
        int bk = b;
        int c = cntM[bk * NPART + t];                       // my slot's count (t = partition block id)
        const unsigned* slot = bucketed + bk * SLABSTRIDE + t * SLOTCAP;
        int* h = sh.sort.h;
        h[t] = 0;
        __syncthreads();
        for (int i = 0; i < c; ++i)
            atomicAdd(&h[(slot[i] >> 16) & 255], 1);
        __syncthreads();
        int myc = h[t];
        // inclusive scan in place on h
        for (int d = 1; d < 256; d <<= 1) {
            int add = (t >= d) ? h[t - d] : 0;
            __syncthreads();
            h[t] += add;
            __syncthreads();
        }
        int node = (bk << 8) + t;
        off[node] = (bk << CAPSH) + h[t] - myc;
        cnt[node] = myc;
        if (t == 255) sh.sort.mtot = h[255];
        __syncthreads();
        for (int i = 0; i < c; ++i) {
            unsigned u = slot[i];
            int low = (u >> 16) & 255;
            int pos = atomicSub(&h[low], 1) - 1;
            sh.sort.s16[pos] = (unsigned short)(u & 0xFFFFu);
        }
        __syncthreads();
        int m = sh.sort.mtot;
        for (int i = t; i < m; i += 256) srcs16[(bk << CAPSH) + i] = sh.sort.s16[i];
        return;
    }

    // ---- MFMA embed: 32 node-rows per block ----
    int eb = b - NBKT;
    int type, q0;
    if (eb < 640)       { type = 0; q0 = eb * 32; }
    else if (eb < 1920) { type = 1; q0 = (eb - 640) * 32; }
    else if (eb < 1928) { type = 2; q0 = (eb - 1920) * 32; }
    else                { type = 3; q0 = (eb - 1928) * 32; }

    {
        const uint4* src = (const uint4*)(WcT + type * 16384);
        uint4* dst = (uint4*)sh.emb.sWt;
#pragma unroll
        for (int i = 0; i < 8; ++i) dst[t + i * 256] = src[t + i * 256];
    }

    int row = t >> 3, part = t & 7;
    int q = q0 + row;
    int id; const float* tab;
    if (type == 0)      { id = fid[q]; tab = feat_tab; }
    else if (type == 1) { id = sid[q]; tab = sent_tab; }
    else if (type == 2) { id = uid[q]; tab = user_tab; }
    else                { id = iid[q]; tab = item_tab; }
    {
        const float4* gsrc = (const float4*)(tab + (long long)id * 128) + part * 4;
        float4 v0 = gsrc[0], v1 = gsrc[1], v2 = gsrc[2], v3 = gsrc[3];
        uint4 p0 = {pk2(v0.x, v0.y), pk2(v0.z, v0.w), pk2(v1.x, v1.y), pk2(v1.z, v1.w)};
        uint4 p1 = {pk2(v2.x, v2.y), pk2(v2.z, v2.w), pk2(v3.x, v3.y), pk2(v3.z, v3.w)};
        uint4* se = (uint4*)&sh.emb.sE[row * 128 + part * 16];
        se[0] = p0; se[1] = p1;
    }
    __syncthreads();

    {
        int lane = t & 63, w = t >> 6;
        int l15 = lane & 15, l4 = lane >> 4;
        int cb = w * 32;
        f32x4 acc00 = {0, 0, 0, 0}, acc01 = {0, 0, 0, 0};
        f32x4 acc10 = {0, 0, 0, 0}, acc11 = {0, 0, 0, 0};
        const unsigned short* sE = sh.emb.sE;
        const unsigned short* sWt = sh.emb.sWt;
#pragma unroll
        for (int kb = 0; kb < 4; ++kb) {
            int ko = kb * 32 + l4 * 8;
            bf16x8 a0 = *(const bf16x8*)&sE[l15 * 128 + ko];
            bf16x8 a1 = *(const bf16x8*)&sE[(l15 + 16) * 128 + ko];
            bf16x8 b0 = *(const bf16x8*)&sWt[(cb + l15) * 128 + ko];
            bf16x8 b1 = *(const bf16x8*)&sWt[(cb + 16 + l15) * 128 + ko];
            acc00 = __builtin_amdgcn_mfma_f32_16x16x32_bf16(a0, b0, acc00, 0, 0, 0);
            acc01 = __builtin_amdgcn_mfma_f32_16x16x32_bf16(a0, b1, acc01, 0, 0, 0);
            acc10 = __builtin_amdgcn_mfma_f32_16x16x32_bf16(a1, b0, acc10, 0, 0, 0);
            acc11 = __builtin_amdgcn_mfma_f32_16x16x32_bf16(a1, b1, acc11, 0, 0, 0);
        }
        unsigned short* sZ = sh.emb.sZ;
#pragma unroll
        for (int reg = 0; reg < 4; ++reg) {
            int r0 = l4 * 4 + reg;
            sZ[r0 * 128 + cb + l15]              = f2bf(acc00[reg]);
            sZ[r0 * 128 + cb + 16 + l15]         = f2bf(acc01[reg]);
            sZ[(r0 + 16) * 128 + cb + l15]       = f2bf(acc10[reg]);
            sZ[(r0 + 16) * 128 + cb + 16 + l15]  = f2bf(acc11[reg]);
        }
    }
    __syncthreads();

    auto nodeof = [&](int qq) -> int {
        if (type == 0) return (qq / 80) * NPGc + (qq % 80);
        if (type == 1) return (qq / 160) * NPGc + 80 + (qq % 160);
        if (type == 2) return qq * NPGc + 240;
        return qq * NPGc + 241;
    };

    {
        int nd = nodeof(q0 + row);
        uint4* zdst = (uint4*)(zb + (size_t)nd * 128 + part * 16);
        const uint4* zsrc = (const uint4*)&sh.emb.sZ[row * 128 + part * 16];
        zdst[0] = zsrc[0]; zdst[1] = zsrc[1];
    }

    if (t < 128) {
        int r = t >> 2, hh = t & 3;
        const unsigned short* zr = &sh.emb.sZ[r * 128 + hh * 32];
        const float* al = attn_l + hh * 32;
        const float* ar_ = attn_r + hh * 32;
        float sl = 0.f, sr = 0.f;
#pragma unroll
        for (int j2 = 0; j2 < 32; ++j2) {
            float zv = bf2f(zr[j2]);
            sl = fmaf(zv, al[j2], sl);
            sr = fmaf(zv, ar_[j2], sr);
        }
        int nd = nodeof(q0 + r);
        el[nd * 4 + hh] = sl;
        er[nd * 4 + hh] = sr;
    }
}

// ---------------- per-dst softmax + aggregate + ELU + score: one wave per output node ----------------
__global__ __launch_bounds__(256) void k_agg(const int* __restrict__ off,
    const int* __restrict__ cnt,
    const unsigned short* __restrict__ src16, const float* __restrict__ el,
    const float* __restrict__ er, const unsigned short* __restrict__ zb,
    const float* __restrict__ w_sent, const float* __restrict__ b_sent,
    const float* __restrict__ w_feat, const float* __restrict__ b_feat,
    float* __restrict__ out)
{
    __shared__ int   ssrc[4][64];
    __shared__ float sex[4][64][4];
    int t = threadIdx.x;
    int w = t >> 6, lane = t & 63;
    int oid = blockIdx.x * 4 + w;           // grid = 61440/4, all waves produce output
    int g = oid / 240, local = oid % 240;
    int n = g * NPGc + local;
    int beg = off[n], deg = cnt[n];
    const float4 er4 = *(const float4*)(er + n * 4);

    int grp = lane >> 4, li = lane & 15;
    int hm = li >> 2;                       // head of cols li*8 .. li*8+7

    float4 den = {0, 0, 0, 0};
    float acc[8] = {0, 0, 0, 0, 0, 0, 0, 0};

    for (int chunk = 0; chunk < deg; chunk += 64) {
        int m = min(64, deg - chunk);
        if (lane < m) {
            int s = (int)src16[beg + chunk + lane];
            float4 l4 = *(const float4*)(el + s * 4);
            float4 e;
            e.x = l4.x + er4.x; e.y = l4.y + er4.y; e.z = l4.z + er4.z; e.w = l4.w + er4.w;
            e.x = e.x > 0.f ? e.x : 0.2f * e.x;
            e.y = e.y > 0.f ? e.y : 0.2f * e.y;
            e.z = e.z > 0.f ? e.z : 0.2f * e.z;
            e.w = e.w > 0.f ? e.w : 0.2f * e.w;
            float4 ex;
            ex.x = expf(e.x); ex.y = expf(e.y); ex.z = expf(e.z); ex.w = expf(e.w);
            den.x += ex.x; den.y += ex.y; den.z += ex.z; den.w += ex.w;
            ssrc[w][lane] = s;
            *(float4*)&sex[w][lane][0] = ex;
        }
        // 8 zb-rows in flight per wave: two edges per 16-lane group per step
        for (int c0 = 0; c0 < m; c0 += 8) {
            int j0 = c0 + grp, j1 = c0 + 4 + grp;
            float ew0 = 0.f, ew1 = 0.f; int s0 = 0, s1 = 0;
            if (j0 < m) { s0 = ssrc[w][j0]; ew0 = sex[w][j0][hm]; }
            if (j1 < m) { s1 = ssrc[w][j1]; ew1 = sex[w][j1][hm]; }
            uint4 u0 = *(const uint4*)(zb + (size_t)s0 * 128 + li * 8);
            uint4 u1 = *(const uint4*)(zb + (size_t)s1 * 128 + li * 8);
            acc[0] = fmaf(ew0, bflo(u0.x), acc[0]);
            acc[1] = fmaf(ew0, bfhi(u0.x), acc[1]);
            acc[2] = fmaf(ew0, bflo(u0.y), acc[2]);
            acc[3] = fmaf(ew0, bfhi(u0.y), acc[3]);
            acc[4] = fmaf(ew0, bflo(u0.z), acc[4]);
            acc[5] = fmaf(ew0, bfhi(u0.z), acc[5]);
            acc[6] = fmaf(ew0, bflo(u0.w), acc[6]);
            acc[7] = fmaf(ew0, bfhi(u0.w), acc[7]);
            acc[0] = fmaf(ew1, bflo(u1.x), acc[0]);
            acc[1] = fmaf(ew1, bfhi(u1.x), acc[1]);
            acc[2] = fmaf(ew1, bflo(u1.y), acc[2]);
            acc[3] = fmaf(ew1, bfhi(u1.y), acc[3]);
            acc[4] = fmaf(ew1, bflo(u1.z), acc[4]);
            acc[5] = fmaf(ew1, bfhi(u1.z), acc[5]);
            acc[6] = fmaf(ew1, bflo(u1.w), acc[6]);
            acc[7] = fmaf(ew1, bfhi(u1.w), acc[7]);
        }
    }

#pragma unroll
    for (int k = 0; k < 8; ++k) {
        acc[k] += __shfl_xor(acc[k], 16);
        acc[k] += __shfl_xor(acc[k], 32);
    }
#pragma unroll
    for (int d = 1; d < 64; d <<= 1) {
        den.x += __shfl_xor(den.x, d); den.y += __shfl_xor(den.y, d);
        den.z += __shfl_xor(den.z, d); den.w += __shfl_xor(den.w, d);
    }

    float dh = (hm == 0 ? den.x : hm == 1 ? den.y : hm == 2 ? den.z : den.w) + 1e-9f;
    float hv[8];
#pragma unroll
    for (int k = 0; k < 8; ++k) {
        float v = acc[k] / dh;
        hv[k] = v > 0.f ? v : expm1f(v);
    }

    const float* wv; float bias; int oidx;
    if (local < FPN) { wv = w_feat; bias = b_feat[0]; oidx = BB * SPN + g * FPN + local; }
    else             { wv = w_sent; bias = b_sent[0]; oidx = g * SPN + (local - FPN); }

    float4 wa = *(const float4*)(wv + li * 8);
    float4 wb = *(const float4*)(wv + li * 8 + 4);
    float p = hv[0] * wa.x + hv[1] * wa.y + hv[2] * wa.z + hv[3] * wa.w
            + hv[4] * wb.x + hv[5] * wb.y + hv[6] * wb.z + hv[7] * wb.w;
#pragma unroll
    for (int d = 1; d < 16; d <<= 1) p += __shfl_xor(p, d);
    if (lane == 0) out[oidx] = p + bias;
}

// ---------------- launcher ----------------
extern "C" void kernel_launch(void* const* d_in, const int* in_sizes, int n_in,
                              void* d_out, int out_size, void* d_ws, size_t ws_size,
                              hipStream_t stream)
{
    const int* fid = (const int*)d_in[0];
    const int* sid = (const int*)d_in[1];
    const int* uid = (const int*)d_in[2];
    const int* iid = (const int*)d_in[3];
    const int* esrc = (const int*)d_in[4];
    const int* edst = (const int*)d_in[5];
    const float* user_tab = (const float*)d_in[6];
    const float* item_tab = (const float*)d_in[7];
    const float* feat_tab = (const float*)d_in[8];
    const float* sent_tab = (const float*)d_in[9];
    const float* W_feat = (const float*)d_in[10];
    const float* W_sent = (const float*)d_in[11];
    const float* W_user = (const float*)d_in[12];
    const float* W_item = (const float*)d_in[13];
    const float* W_gat  = (const float*)d_in[14];
    const float* attn_l = (const float*)d_in[15];
    const float* attn_r = (const float*)d_in[16];
    const float* w_sent = (const float*)d_in[17];
    const float* b_sent = (const float*)d_in[18];
    const float* w_feat = (const float*)d_in[19];
    const float* b_feat = (const float*)d_in[20];
    int E = in_sizes[4];
    float* out = (float*)d_out;

    char* p = (char*)d_ws;
    auto alloc = [&](size_t bytes) { char* r = p; p += ((bytes + 255) & ~(size_t)255); return r; };
    unsigned short* WcT   = (unsigned short*)alloc((size_t)4 * 128 * 128 * sizeof(unsigned short));
    unsigned short* zb    = (unsigned short*)alloc((size_t)NNc * 128 * sizeof(unsigned short));
    float*          el    = (float*)alloc((size_t)NNc * 4 * sizeof(float));
    float*          er    = (float*)alloc((size_t)NNc * 4 * sizeof(float));
    int*            cnt   = (int*)alloc((size_t)NNc * sizeof(int));
    int*            off   = (int*)alloc((size_t)NNc * sizeof(int));
    int*            cntM  = (int*)alloc((size_t)NBKT * NPART * sizeof(int));
    unsigned*       bktd  = (unsigned*)alloc((size_t)NBKT * SLABSTRIDE * sizeof(unsigned));
    unsigned short* srcs16= (unsigned short*)alloc((size_t)NBKT * BCAP * sizeof(unsigned short));

    hipLaunchKernelGGL(k_part, dim3(NPART + 64), dim3(256), 0, stream,
                       esrc, edst, E, cntM, bktd,
                       W_feat, W_sent, W_user, W_item, W_gat, WcT);
    hipLaunchKernelGGL(k_fused, dim3(NBKT + 1936), dim3(256), 0, stream,
                       cntM, bktd, srcs16, off, cnt,
                       fid, sid, uid, iid, feat_tab, sent_tab, user_tab, item_tab,
                       WcT, attn_l, attn_r, zb, el, er);
    hipLaunchKernelGGL(k_agg, dim3(BB * 240 / 4), dim3(256), 0, stream,
                       off, cnt, srcs16, el, er, zb, w_sent, b_sent, w_feat, b_feat, out);
}